// Round 5
// baseline (34.089 us; speedup 1.0000x reference)
//
#include <hip/hip_runtime.h>
#include <hip/hip_bf16.h>
#include <cstdint>
#include <cstddef>

// Problem constants
#define Bsz 16384
#define Esz 16
#define Ssz 64
#define Asz 32
#define Isz 96   // S + A
#define HSz 64
#define HRz 32

#define PT 512        // prep threads
#define NTM 256       // main threads (4 waves)
#define CHUNK 256     // batch rows per main block
#define NTILE 4       // CHUNK / (4 waves * 16 rows)
#define NBH 1024      // Esz * (Bsz/CHUNK) — blocks per half (state | reward)

typedef __attribute__((ext_vector_type(8))) short bf16x8;
typedef __attribute__((ext_vector_type(4))) short short4v;
typedef __attribute__((ext_vector_type(4))) float f32x4;

__device__ __forceinline__ short f2bf(float f) {
    __hip_bfloat16 b = __float2bfloat16(f);   // pairs into v_cvt_pk_bf16_f32
    return *reinterpret_cast<short*>(&b);
}
__device__ __forceinline__ float bf2f(short s) {
    union { uint32_t u; float f; } v; v.u = ((uint32_t)(uint16_t)s) << 16; return v.f;
}

// Workspace layout (bytes)
#define OFF_XBF  0
#define SZ_XBF   (Bsz * Isz * 2)
#define OFF_W1F  (OFF_XBF + SZ_XBF)
#define SZ_W1F   (Esz * Isz * HSz * 2)    // per-e 6144 elems
#define OFF_RW1F (OFF_W1F + SZ_W1F)
#define SZ_RW1F  (Esz * Isz * HRz * 2)    // per-e 3072
#define OFF_W2F  (OFF_RW1F + SZ_RW1F)
#define SZ_W2F   (Esz * HSz * Ssz * 2)    // per-e 4096

// ---- Prep: X -> bf16 row-major; weights -> bf16 MFMA fragment order ----
// Fragment order [e][nt][kk][lane][8]: lane l holds W[k=kk*32+(l>>4)*8+t][n=nt*16+(l&15)]
__global__ void prep_all(const float* __restrict__ state, const float* __restrict__ action,
                         const float* __restrict__ W1, const float* __restrict__ rW1,
                         const float* __restrict__ W2,
                         short* __restrict__ Xbf, short* __restrict__ W1f,
                         short* __restrict__ rW1f, short* __restrict__ W2f) {
    int bid = blockIdx.x;
    if (bid < (Bsz * 24) / PT) {
        int idx = bid * PT + threadIdx.x;            // [0, Bsz*24)
        int row = idx / 24, q = idx - row * 24;
        float4 v = (q < 16)
            ? ((const float4*)(state  + (size_t)row * Ssz))[q]
            : ((const float4*)(action + (size_t)row * Asz))[q - 16];
        short4v p = { f2bf(v.x), f2bf(v.y), f2bf(v.z), f2bf(v.w) };
        *(short4v*)&Xbf[(size_t)row * Isz + q * 4] = p;
    } else {
        int idx = (bid - (Bsz * 24) / PT) * PT + threadIdx.x;  // [0, Esz*13312)
        int e = idx / 13312, r = idx - e * 13312;
        if (r < 6144) {            // W1: [nt<4][kk<3][l][t], k=i, n=h
            int nt = r / 1536, r2 = r % 1536, kk = r2 / 512, r3 = r2 % 512, l = r3 >> 3, t = r3 & 7;
            int i = kk * 32 + (l >> 4) * 8 + t, h = nt * 16 + (l & 15);
            W1f[e * 6144 + r] = f2bf(W1[(size_t)e * Isz * HSz + i * HSz + h]);
        } else if (r < 9216) {     // rW1: [nt<2][kk<3][l][t]
            int r1 = r - 6144;
            int nt = r1 / 1536, r2 = r1 % 1536, kk = r2 / 512, r3 = r2 % 512, l = r3 >> 3, t = r3 & 7;
            int i = kk * 32 + (l >> 4) * 8 + t, h = nt * 16 + (l & 15);
            rW1f[e * 3072 + r1] = f2bf(rW1[(size_t)e * Isz * HRz + i * HRz + h]);
        } else {                   // W2: [nt<4][kk<2][l][t], k=h, n=s
            int r1 = r - 9216;
            int nt = r1 / 1024, r2 = r1 % 1024, kk = r2 / 512, r3 = r2 % 512, l = r3 >> 3, t = r3 & 7;
            int hk = kk * 32 + (l >> 4) * 8 + t, s = nt * 16 + (l & 15);
            W2f[e * 4096 + r1] = f2bf(W2[(size_t)e * HSz * Ssz + hk * Ssz + s]);
        }
    }
}

// ---- Main: blocks [0,NBH) = state MLP, [NBH,2*NBH) = reward MLP ----
// Swapped mfma(Wfrag, Xfrag): D lane: m = lane&15, n = nt*16 + (lane>>4)*4 + j.
__global__ __launch_bounds__(NTM, 3)
void fused_main(const short* __restrict__ Xbf, const short* __restrict__ W1f,
                const short* __restrict__ rW1f, const short* __restrict__ W2f,
                const float* __restrict__ b1, const float* __restrict__ b2,
                const float* __restrict__ rb1, const float* __restrict__ rW2,
                const float* __restrict__ rb2,
                float* __restrict__ outS, float* __restrict__ outR)
{
    const int half = blockIdx.x >> 10;
    const int lb   = blockIdx.x & (NBH - 1);
    const int e    = lb & (Esz - 1);              // 16 consecutive blocks share X rows
    const int c0   = (lb >> 4) * CHUNK;
    const int w = threadIdx.x >> 6, lane = threadIdx.x & 63;
    const int lr = lane & 15, lg = lane >> 4;

    // Per-lane X pointer: row m = lr, bytes lg*16 within the 192 B row
    const short* xbase = Xbf + (size_t)(c0 + w * 16 + lr) * Isz + lg * 8;

    if (half == 0) {
        // ================= STATE PATH =================
        // Per-wave H buffer [m=16][h=64], row stride 68 shorts: b64 writes / b128 reads bank-clean.
        __shared__ __align__(16) short HT[4][16][68];

        bf16x8 w1r[4][3], w2r[4][2];
        {
            const short* p = W1f + e * 6144 + lane * 8;
            #pragma unroll
            for (int nt = 0; nt < 4; ++nt)
                #pragma unroll
                for (int kk = 0; kk < 3; ++kk)
                    w1r[nt][kk] = *(const bf16x8*)(p + (nt * 3 + kk) * 512);
        }
        {
            const short* p = W2f + e * 4096 + lane * 8;
            #pragma unroll
            for (int nt = 0; nt < 4; ++nt)
                #pragma unroll
                for (int kk = 0; kk < 2; ++kk)
                    w2r[nt][kk] = *(const bf16x8*)(p + (nt * 2 + kk) * 512);
        }
        // Biases packed bf16 (saves 32 VGPRs; abs err ~2e-4 << 3.16e-2 threshold)
        short4v b1p[4], b2p[4];
        #pragma unroll
        for (int nt = 0; nt < 4; ++nt) {
            float4 v1 = *(const float4*)&b1[e * HSz + nt * 16 + lg * 4];
            float4 v2 = *(const float4*)&b2[e * Ssz + nt * 16 + lg * 4];
            b1p[nt] = (short4v){ f2bf(v1.x), f2bf(v1.y), f2bf(v1.z), f2bf(v1.w) };
            b2p[nt] = (short4v){ f2bf(v2.x), f2bf(v2.y), f2bf(v2.z), f2bf(v2.w) };
        }

        // Rotating A-prefetch pipeline
        bf16x8 a0 = *(const bf16x8*)(xbase);
        bf16x8 a1 = *(const bf16x8*)(xbase + 32);
        bf16x8 a2 = *(const bf16x8*)(xbase + 64);

        #pragma unroll 1
        for (int t = 0; t < NTILE; ++t) {
            const int tn = (t + 1) & (NTILE - 1);         // wraps: last iter re-reads t=0 (discarded)
            const short* xn = xbase + (size_t)tn * 64 * Isz;
            bf16x8 n0 = *(const bf16x8*)(xn);
            bf16x8 n1 = *(const bf16x8*)(xn + 32);
            bf16x8 n2 = *(const bf16x8*)(xn + 64);

            // Layer 1: D = H^T, lane: m=lr, h = nt*16 + lg*4 + j
            f32x4 accS[4];
            #pragma unroll
            for (int nt = 0; nt < 4; ++nt) {
                f32x4 acc = (f32x4){0.f, 0.f, 0.f, 0.f};
                acc = __builtin_amdgcn_mfma_f32_16x16x32_bf16(w1r[nt][0], a0, acc, 0, 0, 0);
                acc = __builtin_amdgcn_mfma_f32_16x16x32_bf16(w1r[nt][1], a1, acc, 0, 0, 0);
                acc = __builtin_amdgcn_mfma_f32_16x16x32_bf16(w1r[nt][2], a2, acc, 0, 0, 0);
                accS[nt] = acc;
            }
            // H = relu(acc + b1) -> HT (lane holds 4 consecutive h of row lr)
            #pragma unroll
            for (int nt = 0; nt < 4; ++nt) {
                short4v p = { f2bf(fmaxf(accS[nt][0] + bf2f(b1p[nt][0]), 0.f)),
                              f2bf(fmaxf(accS[nt][1] + bf2f(b1p[nt][1]), 0.f)),
                              f2bf(fmaxf(accS[nt][2] + bf2f(b1p[nt][2]), 0.f)),
                              f2bf(fmaxf(accS[nt][3] + bf2f(b1p[nt][3]), 0.f)) };
                *(short4v*)&HT[w][lr][nt * 16 + lg * 4] = p;
            }
            // Layer 2: H frags via b128 (wave-private; same-wave DS ordering)
            bf16x8 h0 = *(const bf16x8*)&HT[w][lr][lg * 8];
            bf16x8 h1 = *(const bf16x8*)&HT[w][lr][32 + lg * 8];
            const int mrow = c0 + t * 64 + w * 16 + lr;
            #pragma unroll
            for (int nt = 0; nt < 4; ++nt) {
                f32x4 acc = (f32x4){0.f, 0.f, 0.f, 0.f};
                acc = __builtin_amdgcn_mfma_f32_16x16x32_bf16(w2r[nt][0], h0, acc, 0, 0, 0);
                acc = __builtin_amdgcn_mfma_f32_16x16x32_bf16(w2r[nt][1], h1, acc, 0, 0, 0);
                float4 o = { acc[0] + bf2f(b2p[nt][0]), acc[1] + bf2f(b2p[nt][1]),
                             acc[2] + bf2f(b2p[nt][2]), acc[3] + bf2f(b2p[nt][3]) };
                *(float4*)&outS[((size_t)e * Bsz + mrow) * Ssz + nt * 16 + lg * 4] = o;
            }
            a0 = n0; a1 = n1; a2 = n2;
        }
    } else {
        // ================= REWARD PATH =================
        bf16x8 rw1r[2][3];
        {
            const short* p = rW1f + e * 3072 + lane * 8;
            #pragma unroll
            for (int nt = 0; nt < 2; ++nt)
                #pragma unroll
                for (int kk = 0; kk < 3; ++kk)
                    rw1r[nt][kk] = *(const bf16x8*)(p + (nt * 3 + kk) * 512);
        }
        float4 rb1v[2], rw2v[2];
        #pragma unroll
        for (int nt = 0; nt < 2; ++nt) {
            rb1v[nt] = *(const float4*)&rb1[e * HRz + nt * 16 + lg * 4];
            rw2v[nt] = *(const float4*)&rW2[e * HRz + nt * 16 + lg * 4];
        }
        const float rb2s = rb2[e];

        bf16x8 a0 = *(const bf16x8*)(xbase);
        bf16x8 a1 = *(const bf16x8*)(xbase + 32);
        bf16x8 a2 = *(const bf16x8*)(xbase + 64);

        #pragma unroll 1
        for (int t = 0; t < NTILE; ++t) {
            const int tn = (t + 1) & (NTILE - 1);
            const short* xn = xbase + (size_t)tn * 64 * Isz;
            bf16x8 n0 = *(const bf16x8*)(xn);
            bf16x8 n1 = *(const bf16x8*)(xn + 32);
            bf16x8 n2 = *(const bf16x8*)(xn + 64);

            f32x4 accR[2];
            #pragma unroll
            for (int nt = 0; nt < 2; ++nt) {
                f32x4 acc = (f32x4){0.f, 0.f, 0.f, 0.f};
                acc = __builtin_amdgcn_mfma_f32_16x16x32_bf16(rw1r[nt][0], a0, acc, 0, 0, 0);
                acc = __builtin_amdgcn_mfma_f32_16x16x32_bf16(rw1r[nt][1], a1, acc, 0, 0, 0);
                acc = __builtin_amdgcn_mfma_f32_16x16x32_bf16(rw1r[nt][2], a2, acc, 0, 0, 0);
                accR[nt] = acc;
            }
            float rp = 0.f;
            #pragma unroll
            for (int nt = 0; nt < 2; ++nt) {
                rp += fmaxf(accR[nt][0] + rb1v[nt].x, 0.f) * rw2v[nt].x;
                rp += fmaxf(accR[nt][1] + rb1v[nt].y, 0.f) * rw2v[nt].y;
                rp += fmaxf(accR[nt][2] + rb1v[nt].z, 0.f) * rw2v[nt].z;
                rp += fmaxf(accR[nt][3] + rb1v[nt].w, 0.f) * rw2v[nt].w;
            }
            rp += __shfl_xor(rp, 16);
            rp += __shfl_xor(rp, 32);
            if (lane < 16) {
                const int mrow = c0 + t * 64 + w * 16 + lr;
                outR[(size_t)e * Bsz + mrow] = fminf(fmaxf(rp + rb2s, -100.f), 200.f);
            }
            a0 = n0; a1 = n1; a2 = n2;
        }
    }
}

extern "C" void kernel_launch(void* const* d_in, const int* in_sizes, int n_in,
                              void* d_out, int out_size, void* d_ws, size_t ws_size,
                              hipStream_t stream) {
    const float* state  = (const float*)d_in[0];
    const float* action = (const float*)d_in[1];
    const float* W1  = (const float*)d_in[2];
    const float* b1  = (const float*)d_in[3];
    const float* W2  = (const float*)d_in[4];
    const float* b2  = (const float*)d_in[5];
    const float* rW1 = (const float*)d_in[6];
    const float* rb1 = (const float*)d_in[7];
    const float* rW2 = (const float*)d_in[8];
    const float* rb2 = (const float*)d_in[9];

    float* outS = (float*)d_out;                      // [E, B, S]
    float* outR = outS + (size_t)Esz * Bsz * Ssz;     // [E, B, 1]

    short* Xbf  = (short*)((char*)d_ws + OFF_XBF);
    short* W1f  = (short*)((char*)d_ws + OFF_W1F);
    short* rW1f = (short*)((char*)d_ws + OFF_RW1F);
    short* W2f  = (short*)((char*)d_ws + OFF_W2F);

    const int prep_blocks = (Bsz * 24) / PT + (Esz * 13312) / PT;   // 768 + 416
    prep_all<<<prep_blocks, PT, 0, stream>>>(state, action, W1, rW1, W2,
                                             Xbf, W1f, rW1f, W2f);
    fused_main<<<2 * NBH, NTM, 0, stream>>>(                        // 2048 blocks
        Xbf, W1f, rW1f, W2f, b1, b2, rb1, rW2, rb2, outS, outR);
}

// Round 6
// 30.455 us; speedup vs baseline: 1.1193x; 1.1193x over previous
//
#include <hip/hip_runtime.h>
#include <hip/hip_bf16.h>
#include <cstdint>
#include <cstddef>

// Problem constants
#define Bsz 16384
#define Esz 16
#define Ssz 64
#define Asz 32
#define Isz 96   // S + A
#define HSz 64
#define HRz 32

#define NTM 256       // 4 waves
#define CHUNK 512     // batch rows per block
#define NTILE 8       // CHUNK / (4 waves * 16 rows)

typedef __attribute__((ext_vector_type(8))) short bf16x8;
typedef __attribute__((ext_vector_type(4))) short short4v;
typedef __attribute__((ext_vector_type(4))) float f32x4;

static __device__ __forceinline__ short f2bf(float f) {
    __hip_bfloat16 b = __float2bfloat16(f);   // pairs into v_cvt_pk_bf16_f32
    return *reinterpret_cast<short*>(&b);
}
static __device__ __forceinline__ float bf2f(short s) {
    union { uint32_t u; float f; } v; v.u = ((uint32_t)(uint16_t)s) << 16; return v.f;
}
static __device__ __forceinline__ bf16x8 pack8(float4 lo, float4 hi) {
    bf16x8 r;
    r[0] = f2bf(lo.x); r[1] = f2bf(lo.y); r[2] = f2bf(lo.z); r[3] = f2bf(lo.w);
    r[4] = f2bf(hi.x); r[5] = f2bf(hi.y); r[6] = f2bf(hi.z); r[7] = f2bf(hi.w);
    return r;
}

// Single fused kernel. One ensemble per block; weights gathered from f32 and
// held in VGPRs; swapped-operand MFMAs (D lane: m = lane&15, n = nt*16+(lane>>4)*4+j).
__global__ __launch_bounds__(NTM, 2)
void fused_all(const float* __restrict__ state, const float* __restrict__ action,
               const float* __restrict__ W1, const float* __restrict__ b1,
               const float* __restrict__ W2, const float* __restrict__ b2,
               const float* __restrict__ rW1, const float* __restrict__ rb1,
               const float* __restrict__ rW2, const float* __restrict__ rb2,
               float* __restrict__ outS, float* __restrict__ outR)
{
    // Per-wave H buffer [m=16][h=64], row stride 68 shorts (136 B):
    // b64 writes / b128 reads both ~2-way max (free). 8704 B total.
    __shared__ __align__(16) short HT[4][16][68];

    const int e  = blockIdx.x & (Esz - 1);     // 16 consecutive blocks share X rows (L2/L3)
    const int c0 = (blockIdx.x >> 4) * CHUNK;
    const int w = threadIdx.x >> 6, lane = threadIdx.x & 63;
    const int lr = lane & 15, lg = lane >> 4;

    // ---- Weight fragments: per-lane gather from f32, convert once ----
    // Fragment (nt,kk): lane holds W[k = kk*32 + lg*8 + t][n = nt*16 + lr], t=0..7.
    bf16x8 w1r[4][3], rw1r[2][3], w2r[4][2];
    {
        const float* base = W1 + (size_t)e * Isz * HSz;
        #pragma unroll
        for (int nt = 0; nt < 4; ++nt)
            #pragma unroll
            for (int kk = 0; kk < 3; ++kk) {
                const float* p = base + (kk * 32 + lg * 8) * HSz + nt * 16 + lr;
                bf16x8 r;
                #pragma unroll
                for (int t = 0; t < 8; ++t) r[t] = f2bf(p[t * HSz]);
                w1r[nt][kk] = r;
            }
    }
    {
        const float* base = rW1 + (size_t)e * Isz * HRz;
        #pragma unroll
        for (int nt = 0; nt < 2; ++nt)
            #pragma unroll
            for (int kk = 0; kk < 3; ++kk) {
                const float* p = base + (kk * 32 + lg * 8) * HRz + nt * 16 + lr;
                bf16x8 r;
                #pragma unroll
                for (int t = 0; t < 8; ++t) r[t] = f2bf(p[t * HRz]);
                rw1r[nt][kk] = r;
            }
    }
    {
        const float* base = W2 + (size_t)e * HSz * Ssz;
        #pragma unroll
        for (int nt = 0; nt < 4; ++nt)
            #pragma unroll
            for (int kk = 0; kk < 2; ++kk) {
                const float* p = base + (kk * 32 + lg * 8) * Ssz + nt * 16 + lr;
                bf16x8 r;
                #pragma unroll
                for (int t = 0; t < 8; ++t) r[t] = f2bf(p[t * Ssz]);
                w2r[nt][kk] = r;
            }
    }

    // ---- Biases packed bf16 (lane's D slots: n = nt*16 + lg*4 + j) ----
    short4v b1p[4], b2p[4], rb1p[2], rw2p[2];
    #pragma unroll
    for (int nt = 0; nt < 4; ++nt) {
        float4 v1 = *(const float4*)&b1[e * HSz + nt * 16 + lg * 4];
        float4 v2 = *(const float4*)&b2[e * Ssz + nt * 16 + lg * 4];
        b1p[nt] = (short4v){ f2bf(v1.x), f2bf(v1.y), f2bf(v1.z), f2bf(v1.w) };
        b2p[nt] = (short4v){ f2bf(v2.x), f2bf(v2.y), f2bf(v2.z), f2bf(v2.w) };
    }
    #pragma unroll
    for (int nt = 0; nt < 2; ++nt) {
        float4 v1 = *(const float4*)&rb1[e * HRz + nt * 16 + lg * 4];
        float4 v2 = *(const float4*)&rW2[e * HRz + nt * 16 + lg * 4];
        rb1p[nt] = (short4v){ f2bf(v1.x), f2bf(v1.y), f2bf(v1.z), f2bf(v1.w) };
        rw2p[nt] = (short4v){ f2bf(v2.x), f2bf(v2.y), f2bf(v2.z), f2bf(v2.w) };
    }
    const float rb2s = rb2[e];

    // ---- X pipeline: f32 loads (prefetched) -> cvt_pk -> bf16 fragments ----
    const int row0 = c0 + w * 16 + lr;               // this lane's base batch row (m = lr)
    const float* sbase = state  + (size_t)row0 * Ssz + lg * 8;
    const float* abase = action + (size_t)row0 * Asz + lg * 8;

    float4 xs0 = *(const float4*)(sbase);
    float4 xs1 = *(const float4*)(sbase + 4);
    float4 xs2 = *(const float4*)(sbase + 32);
    float4 xs3 = *(const float4*)(sbase + 36);
    float4 xa0 = *(const float4*)(abase);
    float4 xa1 = *(const float4*)(abase + 4);
    bf16x8 a0 = pack8(xs0, xs1);
    bf16x8 a1 = pack8(xs2, xs3);
    bf16x8 a2 = pack8(xa0, xa1);

    #pragma unroll 1
    for (int t = 0; t < NTILE; ++t) {
        // Prefetch next tile's f32 rows (wraps to tile 0 on last iter; discarded)
        const int tn = (t + 1) & (NTILE - 1);
        const float* sp = sbase + (size_t)tn * 64 * Ssz;
        const float* ap = abase + (size_t)tn * 64 * Asz;
        float4 ns0 = *(const float4*)(sp);
        float4 ns1 = *(const float4*)(sp + 4);
        float4 ns2 = *(const float4*)(sp + 32);
        float4 ns3 = *(const float4*)(sp + 36);
        float4 na0 = *(const float4*)(ap);
        float4 na1 = *(const float4*)(ap + 4);

        // ---- Layer 1 (state): acc initialized with bias (free add) ----
        f32x4 accS[4];
        #pragma unroll
        for (int nt = 0; nt < 4; ++nt) {
            f32x4 acc = (f32x4){ bf2f(b1p[nt][0]), bf2f(b1p[nt][1]),
                                 bf2f(b1p[nt][2]), bf2f(b1p[nt][3]) };
            acc = __builtin_amdgcn_mfma_f32_16x16x32_bf16(w1r[nt][0], a0, acc, 0, 0, 0);
            acc = __builtin_amdgcn_mfma_f32_16x16x32_bf16(w1r[nt][1], a1, acc, 0, 0, 0);
            acc = __builtin_amdgcn_mfma_f32_16x16x32_bf16(w1r[nt][2], a2, acc, 0, 0, 0);
            accS[nt] = acc;
        }
        // ---- Layer 1 (reward) ----
        f32x4 accR[2];
        #pragma unroll
        for (int nt = 0; nt < 2; ++nt) {
            f32x4 acc = (f32x4){ bf2f(rb1p[nt][0]), bf2f(rb1p[nt][1]),
                                 bf2f(rb1p[nt][2]), bf2f(rb1p[nt][3]) };
            acc = __builtin_amdgcn_mfma_f32_16x16x32_bf16(rw1r[nt][0], a0, acc, 0, 0, 0);
            acc = __builtin_amdgcn_mfma_f32_16x16x32_bf16(rw1r[nt][1], a1, acc, 0, 0, 0);
            acc = __builtin_amdgcn_mfma_f32_16x16x32_bf16(rw1r[nt][2], a2, acc, 0, 0, 0);
            accR[nt] = acc;
        }

        // ---- H = relu(accS) -> HT (lane holds 4 consecutive h of row lr) ----
        #pragma unroll
        for (int nt = 0; nt < 4; ++nt) {
            short4v p = { f2bf(fmaxf(accS[nt][0], 0.f)),
                          f2bf(fmaxf(accS[nt][1], 0.f)),
                          f2bf(fmaxf(accS[nt][2], 0.f)),
                          f2bf(fmaxf(accS[nt][3], 0.f)) };
            *(short4v*)&HT[w][lr][nt * 16 + lg * 4] = p;
        }

        // ---- Reward layer 2 in registers ----
        float rp = 0.f;
        #pragma unroll
        for (int nt = 0; nt < 2; ++nt) {
            rp += fmaxf(accR[nt][0], 0.f) * bf2f(rw2p[nt][0]);
            rp += fmaxf(accR[nt][1], 0.f) * bf2f(rw2p[nt][1]);
            rp += fmaxf(accR[nt][2], 0.f) * bf2f(rw2p[nt][2]);
            rp += fmaxf(accR[nt][3], 0.f) * bf2f(rw2p[nt][3]);
        }
        rp += __shfl_xor(rp, 16);
        rp += __shfl_xor(rp, 32);
        if (lane < 16)
            outR[(size_t)e * Bsz + row0 + t * 64] = fminf(fmaxf(rp + rb2s, -100.f), 200.f);

        // ---- Layer 2 (state): H frags via b128 (wave-private, in-order DS) ----
        bf16x8 h0 = *(const bf16x8*)&HT[w][lr][lg * 8];
        bf16x8 h1 = *(const bf16x8*)&HT[w][lr][32 + lg * 8];
        #pragma unroll
        for (int nt = 0; nt < 4; ++nt) {
            f32x4 acc = (f32x4){ bf2f(b2p[nt][0]), bf2f(b2p[nt][1]),
                                 bf2f(b2p[nt][2]), bf2f(b2p[nt][3]) };
            acc = __builtin_amdgcn_mfma_f32_16x16x32_bf16(w2r[nt][0], h0, acc, 0, 0, 0);
            acc = __builtin_amdgcn_mfma_f32_16x16x32_bf16(w2r[nt][1], h1, acc, 0, 0, 0);
            float4 o = { acc[0], acc[1], acc[2], acc[3] };
            *(float4*)&outS[((size_t)e * Bsz + row0 + t * 64) * Ssz + nt * 16 + lg * 4] = o;
        }

        // ---- Convert prefetched f32 -> current fragments (vmcnt wait lands here) ----
        a0 = pack8(ns0, ns1);
        a1 = pack8(ns2, ns3);
        a2 = pack8(na0, na1);
    }
}

extern "C" void kernel_launch(void* const* d_in, const int* in_sizes, int n_in,
                              void* d_out, int out_size, void* d_ws, size_t ws_size,
                              hipStream_t stream) {
    const float* state  = (const float*)d_in[0];
    const float* action = (const float*)d_in[1];
    const float* W1  = (const float*)d_in[2];
    const float* b1  = (const float*)d_in[3];
    const float* W2  = (const float*)d_in[4];
    const float* b2  = (const float*)d_in[5];
    const float* rW1 = (const float*)d_in[6];
    const float* rb1 = (const float*)d_in[7];
    const float* rW2 = (const float*)d_in[8];
    const float* rb2 = (const float*)d_in[9];

    float* outS = (float*)d_out;                      // [E, B, S]
    float* outR = outS + (size_t)Esz * Bsz * Ssz;     // [E, B, 1]

    fused_all<<<Esz * (Bsz / CHUNK), NTM, 0, stream>>>(   // 512 blocks, 1 generation
        state, action, W1, b1, W2, b2, rW1, rb1, rW2, rb2, outS, outR);
}